// Round 20
// baseline (79.831 us; speedup 1.0000x reference)
//
#include <hip/hip_runtime.h>

#define HID 128
#define NODES 2032
#define NPT 127
#define NW 1024

typedef _Float16 f16x8 __attribute__((ext_vector_type(8)));
typedef _Float16 f16x4 __attribute__((ext_vector_type(4)));
typedef float f32x4 __attribute__((ext_vector_type(4)));

// post-order index (within one 127-node tree) of the p-th node at a level
// whose subtree size is sst = 2^(L+1)-1
__device__ __forceinline__ int tree_idx(int p, int sst) {
  return (p + 1) * sst + p - __popc(p) - 1;
}
// swizzled byte address in a [R][256] fp16 tile with 512B rows
__device__ __forceinline__ int cswz(int row, int colbyte) {
  return row * 512 + (colbyte ^ ((row & 31) << 4));
}
// select element i (0..7) from 2 float4 regs (pure cndmask tree, no scratch)
__device__ __forceinline__ float pick8(float4 a, float4 b, int i) {
  float4 s = (i & 4) ? b : a;
  float lo = (i & 1) ? s.y : s.x;
  float hi = (i & 1) ? s.w : s.z;
  return (i & 2) ? hi : lo;
}

// Device-coherent 4B access: relaxed agent-scope atomics -> sc1 accesses at
// the device coherence point. No fences, no L2 writeback/invalidate.
__device__ __forceinline__ unsigned int cload(const void* p) {
  return __hip_atomic_load((const unsigned int*)p, __ATOMIC_RELAXED, __HIP_MEMORY_SCOPE_AGENT);
}
__device__ __forceinline__ void cstore(void* p, unsigned int v) {
  __hip_atomic_store((unsigned int*)p, v, __ATOMIC_RELAXED, __HIP_MEMORY_SCOPE_AGENT);
}
__device__ __forceinline__ float cloadf(const void* p) {
  union { unsigned int u; float f; } c; c.u = cload(p); return c.f;
}
__device__ __forceinline__ void cstoref(void* p, float f) {
  union { float f; unsigned int u; } c; c.f = f; cstore(p, c.u);
}

// Pure-relaxed tree barrier for 256 blocks: 16 groups x 16 -> root ->
// 16 per-group release flags (<=16 pollers per flag line). Every wave drains
// its sc1 stores (s_waitcnt vmcnt(0)) BEFORE arriving.
__device__ __forceinline__ void gbar(int* sb, int ph) {
  asm volatile("s_waitcnt vmcnt(0)" ::: "memory");
  __syncthreads();
  if (threadIdx.x == 0) {
    int* base = sb + ph * 1024;
    const int grp = blockIdx.x & 15;
    int v = __hip_atomic_fetch_add(base + grp * 32, 1, __ATOMIC_RELAXED, __HIP_MEMORY_SCOPE_AGENT);
    if (v == 15) {
      int r = __hip_atomic_fetch_add(base + 768, 1, __ATOMIC_RELAXED, __HIP_MEMORY_SCOPE_AGENT);
      if (r == 15) {
#pragma unroll
        for (int gg = 0; gg < 16; ++gg)
          __hip_atomic_store(base + 512 + gg * 16, 1, __ATOMIC_RELAXED, __HIP_MEMORY_SCOPE_AGENT);
      }
    }
    while (!__hip_atomic_load(base + 512 + grp * 16, __ATOMIC_RELAXED, __HIP_MEMORY_SCOPE_AGENT))
      __builtin_amdgcn_s_sleep(4);
  }
  __syncthreads();
}

// Persistent kernel, 256 blocks = (h, part), 1024 threads = 16 waves, 1/CU.
// A = V[h] fp16 in 128 KB swizzled LDS, staged WAVE-PRIVATE (no barrier):
// wave w writes and MFMA-reads exactly k-rows [16w,16w+16). 6 levels,
// 32-node C-tiles, 2 syncs/tile; lv0 stages from embed with leaf-Hgt from
// prefetch regs. All cross-block traffic via sc1 atomics; 6 relaxed
// barriers; log-softmax epilogue in-kernel.
__global__ __launch_bounds__(1024, 1) void rntn_kernel(
    const float* __restrict__ V, const float* __restrict__ W, const float* __restrict__ bb,
    const float* __restrict__ embed, const int* __restrict__ word_idx,
    const float* __restrict__ Wout, const float* __restrict__ Wb,
    _Float16* __restrict__ H16A, _Float16* __restrict__ H16B,
    float* __restrict__ Hgt, float* __restrict__ out, int* __restrict__ syncb)
{
  __shared__ _Float16 Alds[256 * 256];  // 128 KB swizzled A (row = k, 512B)
  __shared__ _Float16 Ct[32 * 256];     // 16 KB swizzled C-tile
  __shared__ float red[16][32];

  const int bid = blockIdx.x;
  const int h = bid >> 1, part = bid & 1;
  const int tid = threadIdx.x, lane = tid & 63, w = tid >> 6;   // w in [0,16)
  const int lo16 = lane & 15, q = lane >> 4;
  const int nidx = tid & 31, oct = tid >> 5;   // lv>0 stage: 32 nodes x 32 octs
  const int r16 = tid >> 4, seg = tid & 15;    // lv0 stage: 64 rows x 16 segs
  const int hseg = h >> 3, hcomp = h & 7;      // which seg/elem holds col h
  char* ab = (char*)Alds;
  char* cb = (char*)Ct;

  // ---- lv0 tile-0 embed gather FIRST (overlaps the A read below)
  float4 ef0, ef1;
  {
    const int nodeL = r16 >> 1, child = r16 & 1;
    const int lp = 2 * (part * 256 + nodeL) + child;
    const int tt = lp >> 6, pp = lp & 63;
    const int g = tt * NPT + 2 * pp - __popc(pp);
    const int wi = word_idx[g];
    const float* src = embed + (size_t)wi * HID + seg * 8;
    ef0 = ((const float4*)src)[0]; ef1 = ((const float4*)src)[1];
  }

  // ---- stage A, WAVE-PRIVATE: thread covers quarter row (tid>>2); wave w
  // writes exactly rows [16w,16w+16) and only wave w's MFMA reads them.
  {
    const int arow = tid >> 2, aqtr = tid & 3;
    const float* src = V + (size_t)h * 65536 + (size_t)arow * 256 + aqtr * 64;
#pragma unroll
    for (int u2 = 0; u2 < 8; ++u2) {
      const float4 a = ((const float4*)src)[u2 * 2];
      const float4 b2 = ((const float4*)src)[u2 * 2 + 1];
      f16x8 v;
      v[0] = (_Float16)a.x;  v[1] = (_Float16)a.y;
      v[2] = (_Float16)a.z;  v[3] = (_Float16)a.w;
      v[4] = (_Float16)b2.x; v[5] = (_Float16)b2.y;
      v[6] = (_Float16)b2.z; v[7] = (_Float16)b2.w;
      *(f16x8*)(ab + cswz(arow, aqtr * 128 + u2 * 16)) = v;
    }
  }
  // ---- W strip -> registers (wave w covers k in [16w, 16w+16))
  f32x4 wk;
  {
    const int kb = w * 16 + q * 4;
#pragma unroll
    for (int i = 0; i < 4; ++i)
      wk[i] = W[(size_t)(kb + i) * HID + h];
  }
  const float bh = bb[h];

  for (int lv = 0; lv < 6; ++lv) {
    const int m = 512 >> lv;
    const int lognpt = 5 - lv;
    const int sst = (1 << (lv + 2)) - 1;
    _Float16* Hp = (lv & 1) ? H16A : H16B;   // prev-level buffer (lv0 unused)
    _Float16* Hn = (lv & 1) ? H16B : H16A;
    const int nodes_blk = m >> 1;
    const int n_start = part * nodes_blk;
    const int ntiles = (nodes_blk + 31) >> 5;

    unsigned int u[4];
    // ---- entry: prefetch + stage tile 0
    if (lv == 0) {
      const int nodeL = r16 >> 1, child = r16 & 1;
      f16x8 v0;
      v0[0] = (_Float16)ef0.x; v0[1] = (_Float16)ef0.y;
      v0[2] = (_Float16)ef0.z; v0[3] = (_Float16)ef0.w;
      v0[4] = (_Float16)ef1.x; v0[5] = (_Float16)ef1.y;
      v0[6] = (_Float16)ef1.z; v0[7] = (_Float16)ef1.w;
      *(f16x8*)(cb + cswz(nodeL, child * 256 + seg * 16)) = v0;
      if (seg == hseg) {        // leaf Hgt from regs (fp32-exact)
        const int lp = 2 * (n_start + nodeL) + child;
        const int tt = lp >> 6, pp = lp & 63;
        const int g = tt * NPT + 2 * pp - __popc(pp);
        cstoref(Hgt + (size_t)h * 2048 + g, pick8(ef0, ef1, hcomp));
      }
    } else {
      const int nn0 = nodes_blk > 32 ? 32 : nodes_blk;
      if (nidx < nn0) {
#pragma unroll
        for (int j = 0; j < 4; ++j)
          u[j] = cload(Hp + (size_t)(oct * 4 + j) * NW + 2 * (n_start + nidx));
        union { f16x4 v; unsigned short s[4]; } a0, a1;
#pragma unroll
        for (int j = 0; j < 4; ++j) {
          a0.s[j] = (unsigned short)(u[j] & 0xffffu);
          a1.s[j] = (unsigned short)(u[j] >> 16);
        }
        *(f16x4*)(cb + cswz(nidx, oct * 8)) = a0.v;
        *(f16x4*)(cb + cswz(nidx, 256 + oct * 8)) = a1.v;
      }
    }
    __syncthreads();                 // Ct(tile 0) ready

    for (int t = 0; t < ntiles; ++t) {
      const int nb = n_start + t * 32;
      int nn = nodes_blk - t * 32; if (nn > 32) nn = 32;
      const int ncf = (nn + 15) >> 4;
      int nnn = nodes_blk - (t + 1) * 32; if (nnn > 32) nnn = 32;

      // ---- prefetch tile t+1 (latency hides under MFMA + step-2)
      if (t + 1 < ntiles) {
        if (lv == 0) {
          const int nodeL = r16 >> 1, child = r16 & 1;
          const int lp = 2 * (nb + 32 + nodeL) + child;
          const int tt = lp >> 6, pp = lp & 63;
          const int g = tt * NPT + 2 * pp - __popc(pp);
          const int wi = word_idx[g];
          const float* src = embed + (size_t)wi * HID + seg * 8;
          ef0 = ((const float4*)src)[0]; ef1 = ((const float4*)src)[1];
        } else {
          if (nidx < nnn) {
#pragma unroll
            for (int j = 0; j < 4; ++j)
              u[j] = cload(Hp + (size_t)(oct * 4 + j) * NW + 2 * (nb + 32 + nidx));
          }
        }
      }

      f32x4 acc[2];
#pragma unroll
      for (int cf = 0; cf < 2; ++cf) { f32x4 z = {0.f, 0.f, 0.f, 0.f}; acc[cf] = z; }

#pragma unroll
      for (int lc = 0; lc < 8; ++lc) {
        const f16x8 Af = *(const f16x8*)(ab + cswz(w * 16 + lo16, lc * 64 + q * 16));
#pragma unroll
        for (int cf = 0; cf < 2; ++cf) {
          if (cf < ncf) {
            const int nl = cf * 16 + lo16;
            const f16x8 Bf = *(const f16x8*)(cb + cswz(nl, lc * 64 + q * 16));
            acc[cf] = __builtin_amdgcn_mfma_f32_16x16x32_f16(Af, Bf, acc[cf], 0, 0, 0);
          }
        }
      }

      // ---- step-2: part[n] = sum_k c_n[k]*(T[k,n] + W[k,h]); c fp16 from LDS
      float pt[2];
#pragma unroll
      for (int cf = 0; cf < 2; ++cf) {
        pt[cf] = 0.f;
        if (cf < ncf) {
          const int nl = cf * 16 + lo16;
          const int kb = w * 16 + q * 4;
          const f16x4 cv = *(const f16x4*)(cb + cswz(nl, kb * 2));
          pt[cf] = (float)cv[0] * (acc[cf][0] + wk[0])
                 + (float)cv[1] * (acc[cf][1] + wk[1])
                 + (float)cv[2] * (acc[cf][2] + wk[2])
                 + (float)cv[3] * (acc[cf][3] + wk[3]);
        }
      }
#pragma unroll
      for (int cf = 0; cf < 2; ++cf) {
        pt[cf] += __shfl_xor(pt[cf], 16);
        pt[cf] += __shfl_xor(pt[cf], 32);
      }
      if (q == 0) {
#pragma unroll
        for (int cf = 0; cf < 2; ++cf)
          if (cf < ncf) red[w][cf * 16 + lo16] = pt[cf];
      }
      __syncthreads();               // red ready; all Ct reads done

      // ---- store (reads red only) || stage tile t+1 into Ct (from regs)
      if (tid < (nn >> 1)) {
        float x0 = bh, x1 = bh;
#pragma unroll
        for (int ww = 0; ww < 16; ++ww) {
          x0 += red[ww][2 * tid];
          x1 += red[ww][2 * tid + 1];
        }
        const float t0 = tanhf(x0), t1 = tanhf(x1);
        union { _Float16 f; unsigned short s; } c0, c1;
        c0.f = (_Float16)t0; c1.f = (_Float16)t1;
        const int n0 = nb + 2 * tid;
        cstore(Hn + (size_t)h * NW + n0, (unsigned)c0.s | ((unsigned)c1.s << 16));
        const int mask = (1 << lognpt) - 1;
        const int g0 = ((n0) >> lognpt) * NPT + tree_idx(n0 & mask, sst);
        const int g1 = ((n0 + 1) >> lognpt) * NPT + tree_idx((n0 + 1) & mask, sst);
        cstoref(Hgt + (size_t)h * 2048 + g0, t0);
        cstoref(Hgt + (size_t)h * 2048 + g1, t1);
      }
      if (t + 1 < ntiles) {
        if (lv == 0) {
          const int nodeL = r16 >> 1, child = r16 & 1;
          f16x8 v0;
          v0[0] = (_Float16)ef0.x; v0[1] = (_Float16)ef0.y;
          v0[2] = (_Float16)ef0.z; v0[3] = (_Float16)ef0.w;
          v0[4] = (_Float16)ef1.x; v0[5] = (_Float16)ef1.y;
          v0[6] = (_Float16)ef1.z; v0[7] = (_Float16)ef1.w;
          *(f16x8*)(cb + cswz(nodeL, child * 256 + seg * 16)) = v0;
          if (seg == hseg) {
            const int lp = 2 * (nb + 32 + nodeL) + child;
            const int tt = lp >> 6, pp = lp & 63;
            const int g = tt * NPT + 2 * pp - __popc(pp);
            cstoref(Hgt + (size_t)h * 2048 + g, pick8(ef0, ef1, hcomp));
          }
        } else {
          if (nidx < nnn) {
            union { f16x4 v; unsigned short s[4]; } a0, a1;
#pragma unroll
            for (int j = 0; j < 4; ++j) {
              a0.s[j] = (unsigned short)(u[j] & 0xffffu);
              a1.s[j] = (unsigned short)(u[j] >> 16);
            }
            *(f16x4*)(cb + cswz(nidx, oct * 8)) = a0.v;
            *(f16x4*)(cb + cswz(nidx, 256 + oct * 8)) = a1.v;
          }
        }
      }
      __syncthreads();               // Ct(t+1) ready; red free
    }
    gbar(syncb, lv);
  }

  // ---- output epilogue: block b (<127) owns nodes b*16 .. b*16+15
  if (bid < 127 && tid < 256) {
    const int node = bid * 16 + (tid >> 4);
    const int hs = tid & 15;
    float l0 = 0.f, l1 = 0.f, l2 = 0.f, l3 = 0.f, l4 = 0.f;
#pragma unroll
    for (int j = 0; j < 8; ++j) {
      const int hh = hs + j * 16;
      const float x = cloadf(Hgt + (size_t)hh * 2048 + node);
      const float* wr = Wout + (size_t)hh * 5;
      l0 += x * wr[0]; l1 += x * wr[1]; l2 += x * wr[2];
      l3 += x * wr[3]; l4 += x * wr[4];
    }
#pragma unroll
    for (int d = 1; d < 16; d <<= 1) {
      l0 += __shfl_xor(l0, d); l1 += __shfl_xor(l1, d); l2 += __shfl_xor(l2, d);
      l3 += __shfl_xor(l3, d); l4 += __shfl_xor(l4, d);
    }
    if (hs == 0) {
      l0 += Wb[0]; l1 += Wb[1]; l2 += Wb[2]; l3 += Wb[3]; l4 += Wb[4];
      const float mm = fmaxf(fmaxf(fmaxf(l0, l1), fmaxf(l2, l3)), l4);
      const float ss = expf(l0 - mm) + expf(l1 - mm) + expf(l2 - mm)
                     + expf(l3 - mm) + expf(l4 - mm);
      const float lse = mm + logf(ss);
      float* o = out + (size_t)node * 5;
      o[0] = l0 - lse; o[1] = l1 - lse; o[2] = l2 - lse; o[3] = l3 - lse; o[4] = l4 - lse;
    }
  }
}

extern "C" void kernel_launch(void* const* d_in, const int* in_sizes, int n_in,
                              void* d_out, int out_size, void* d_ws, size_t ws_size,
                              hipStream_t stream) {
  const float* embed = (const float*)d_in[0];
  const float* V     = (const float*)d_in[1];
  const float* W     = (const float*)d_in[2];
  const float* b     = (const float*)d_in[3];
  const float* Wout  = (const float*)d_in[4];
  const float* Woutb = (const float*)d_in[5];
  // d_in[6/8/9] = is_leaf/left/right: tree structure is implicit
  const int* word_idx = (const int*)d_in[7];
  float* out = (float*)d_out;

  // ws: H16A | H16B | Hgt | sync
  char* wsb = (char*)d_ws;
  _Float16* H16A = (_Float16*)wsb;                      // 128*1024*2 = 262144
  _Float16* H16B = (_Float16*)(wsb + 262144);           //              262144
  float*    Hgt  = (float*)(wsb + 524288);              // 128*2048*4 = 1048576
  int*     syncb = (int*)(wsb + 1572864);               //               24576

  hipMemsetAsync(syncb, 0, 24576, stream);
  rntn_kernel<<<256, 1024, 0, stream>>>(V, W, b, embed, word_idx, Wout, Woutb,
                                        H16A, H16B, Hgt, out, syncb);
}

// Round 21
// 71.224 us; speedup vs baseline: 1.1208x; 1.1208x over previous
//
#include <hip/hip_runtime.h>

#define HID 128
#define NODES 2032
#define NPT 127
#define NW 1024

typedef _Float16 f16x8 __attribute__((ext_vector_type(8)));
typedef _Float16 f16x4 __attribute__((ext_vector_type(4)));
typedef float f32x4 __attribute__((ext_vector_type(4)));

// post-order index (within one 127-node tree) of the p-th node at a level
// whose subtree size is sst = 2^(L+1)-1
__device__ __forceinline__ int tree_idx(int p, int sst) {
  return (p + 1) * sst + p - __popc(p) - 1;
}
// swizzled byte address in a [R][256] fp16 tile with 512B rows
__device__ __forceinline__ int cswz(int row, int colbyte) {
  return row * 512 + (colbyte ^ ((row & 31) << 4));
}
// select element i (0..15) from 4 float4 regs (pure cndmask tree, no scratch)
__device__ __forceinline__ float pick16(float4 a, float4 b, float4 c, float4 d, int i) {
  float4 s0x = (i & 8) ? c : a;
  float4 s1x = (i & 8) ? d : b;
  float4 s = (i & 4) ? s1x : s0x;
  float lo = (i & 1) ? s.y : s.x;
  float hi = (i & 1) ? s.w : s.z;
  return (i & 2) ? hi : lo;
}

// Device-coherent 4B access: relaxed agent-scope atomics -> sc1 accesses at
// the device coherence point. No fences, no L2 writeback/invalidate.
__device__ __forceinline__ unsigned int cload(const void* p) {
  return __hip_atomic_load((const unsigned int*)p, __ATOMIC_RELAXED, __HIP_MEMORY_SCOPE_AGENT);
}
__device__ __forceinline__ void cstore(void* p, unsigned int v) {
  __hip_atomic_store((unsigned int*)p, v, __ATOMIC_RELAXED, __HIP_MEMORY_SCOPE_AGENT);
}
__device__ __forceinline__ float cloadf(const void* p) {
  union { unsigned int u; float f; } c; c.u = cload(p); return c.f;
}
__device__ __forceinline__ void cstoref(void* p, float f) {
  union { float f; unsigned int u; } c; c.f = f; cstore(p, c.u);
}

// Pure-relaxed tree barrier for 256 blocks: 16 groups x 16 -> root ->
// 16 per-group release flags (<=16 pollers per flag line). Every wave drains
// its sc1 stores (s_waitcnt vmcnt(0)) BEFORE arriving.
__device__ __forceinline__ void gbar(int* sb, int ph) {
  asm volatile("s_waitcnt vmcnt(0)" ::: "memory");
  __syncthreads();
  if (threadIdx.x == 0) {
    int* base = sb + ph * 1024;
    const int grp = blockIdx.x & 15;
    int v = __hip_atomic_fetch_add(base + grp * 32, 1, __ATOMIC_RELAXED, __HIP_MEMORY_SCOPE_AGENT);
    if (v == 15) {
      int r = __hip_atomic_fetch_add(base + 768, 1, __ATOMIC_RELAXED, __HIP_MEMORY_SCOPE_AGENT);
      if (r == 15) {
#pragma unroll
        for (int gg = 0; gg < 16; ++gg)
          __hip_atomic_store(base + 512 + gg * 16, 1, __ATOMIC_RELAXED, __HIP_MEMORY_SCOPE_AGENT);
      }
    }
    while (!__hip_atomic_load(base + 512 + grp * 16, __ATOMIC_RELAXED, __HIP_MEMORY_SCOPE_AGENT))
      __builtin_amdgcn_s_sleep(4);
  }
  __syncthreads();
}

// Persistent kernel, 256 blocks = (h, part), 512 threads = 8 waves, 1 block/CU.
// A = V[h] fp16 in 128 KB swizzled LDS, staged WAVE-PRIVATE (no barrier).
// 6 levels, 32-node C-tiles, 2 syncs/tile pipeline; lv0 stages from embed
// with leaf-Hgt extracted from prefetch regs. All cross-block traffic via
// sc1 atomics; 6 relaxed barriers; log-softmax epilogue in-kernel.
__global__ __launch_bounds__(512, 1) void rntn_kernel(
    const float* __restrict__ V, const float* __restrict__ W, const float* __restrict__ bb,
    const float* __restrict__ embed, const int* __restrict__ word_idx,
    const float* __restrict__ Wout, const float* __restrict__ Wb,
    _Float16* __restrict__ H16A, _Float16* __restrict__ H16B,
    float* __restrict__ Hgt, float* __restrict__ out, int* __restrict__ syncb)
{
  __shared__ _Float16 Alds[256 * 256];  // 128 KB swizzled A (row = k, 512B)
  __shared__ _Float16 Ct[32 * 256];     // 16 KB swizzled C-tile
  __shared__ float red[8][32];

  const int bid = blockIdx.x;
  const int h = bid >> 1, part = bid & 1;
  const int tid = threadIdx.x, lane = tid & 63, w = tid >> 6;   // w in [0,8)
  const int lo16 = lane & 15, q = lane >> 4;
  const int nidx = tid & 31, oct = tid >> 5;   // lv>0 stage: 32 nodes x 16 octs
  const int r8 = tid >> 3, seg = tid & 7;      // lv0 stage: 64 rows x 8 segs
  const int hseg = h >> 4, hcomp = h & 15;     // which seg/elem holds col h
  char* ab = (char*)Alds;
  char* cb = (char*)Ct;

  // ---- lv0 tile-0 embed gather FIRST (overlaps the A read below)
  float4 ef0, ef1, ef2, ef3;
  {
    const int nodeL = r8 >> 1, child = r8 & 1;
    const int lp = 2 * (part * 256 + nodeL) + child;
    const int tt = lp >> 6, pp = lp & 63;
    const int g = tt * NPT + 2 * pp - __popc(pp);
    const int wi = word_idx[g];
    const float* src = embed + (size_t)wi * HID + seg * 16;
    ef0 = ((const float4*)src)[0]; ef1 = ((const float4*)src)[1];
    ef2 = ((const float4*)src)[2]; ef3 = ((const float4*)src)[3];
  }

  // ---- stage A, WAVE-PRIVATE: thread covers half of row (tid>>1); wave w
  // writes exactly rows [32w,32w+32) and only wave w's MFMA reads them.
  {
    const int arow = tid >> 1, ahalf = tid & 1;
    const float* src = V + (size_t)h * 65536 + (size_t)arow * 256 + ahalf * 128;
#pragma unroll
    for (int u2 = 0; u2 < 16; ++u2) {
      const float4 a = ((const float4*)src)[u2 * 2];
      const float4 b2 = ((const float4*)src)[u2 * 2 + 1];
      f16x8 v;
      v[0] = (_Float16)a.x;  v[1] = (_Float16)a.y;
      v[2] = (_Float16)a.z;  v[3] = (_Float16)a.w;
      v[4] = (_Float16)b2.x; v[5] = (_Float16)b2.y;
      v[6] = (_Float16)b2.z; v[7] = (_Float16)b2.w;
      *(f16x8*)(ab + cswz(arow, ahalf * 256 + u2 * 16)) = v;
    }
  }
  // ---- W strip -> registers (wave w covers k in [32w, 32w+32))
  f32x4 wk[2];
#pragma unroll
  for (int rf = 0; rf < 2; ++rf) {
    const int kb = w * 32 + rf * 16 + q * 4;
#pragma unroll
    for (int i = 0; i < 4; ++i)
      wk[rf][i] = W[(size_t)(kb + i) * HID + h];
  }
  const float bh = bb[h];

  for (int lv = 0; lv < 6; ++lv) {
    const int m = 512 >> lv;
    const int lognpt = 5 - lv;
    const int sst = (1 << (lv + 2)) - 1;
    _Float16* Hp = (lv & 1) ? H16A : H16B;   // prev-level buffer (lv0 unused)
    _Float16* Hn = (lv & 1) ? H16B : H16A;
    const int nodes_blk = m >> 1;
    const int n_start = part * nodes_blk;
    const int ntiles = (nodes_blk + 31) >> 5;

    unsigned int u[8];
    // ---- entry: prefetch + stage tile 0
    if (lv == 0) {
      const int nodeL = r8 >> 1, child = r8 & 1;
      f16x8 v0, v1;
      v0[0] = (_Float16)ef0.x; v0[1] = (_Float16)ef0.y;
      v0[2] = (_Float16)ef0.z; v0[3] = (_Float16)ef0.w;
      v0[4] = (_Float16)ef1.x; v0[5] = (_Float16)ef1.y;
      v0[6] = (_Float16)ef1.z; v0[7] = (_Float16)ef1.w;
      v1[0] = (_Float16)ef2.x; v1[1] = (_Float16)ef2.y;
      v1[2] = (_Float16)ef2.z; v1[3] = (_Float16)ef2.w;
      v1[4] = (_Float16)ef3.x; v1[5] = (_Float16)ef3.y;
      v1[6] = (_Float16)ef3.z; v1[7] = (_Float16)ef3.w;
      *(f16x8*)(cb + cswz(nodeL, child * 256 + seg * 32)) = v0;
      *(f16x8*)(cb + cswz(nodeL, child * 256 + seg * 32 + 16)) = v1;
      if (seg == hseg) {        // leaf Hgt from regs (fp32-exact)
        const int lp = 2 * (n_start + nodeL) + child;
        const int tt = lp >> 6, pp = lp & 63;
        const int g = tt * NPT + 2 * pp - __popc(pp);
        cstoref(Hgt + (size_t)h * 2048 + g, pick16(ef0, ef1, ef2, ef3, hcomp));
      }
    } else {
      const int nn0 = nodes_blk > 32 ? 32 : nodes_blk;
      if (nidx < nn0) {
#pragma unroll
        for (int j = 0; j < 8; ++j)
          u[j] = cload(Hp + (size_t)(oct * 8 + j) * NW + 2 * (n_start + nidx));
        union { f16x8 v; unsigned short s[8]; } a0, a1;
#pragma unroll
        for (int j = 0; j < 8; ++j) {
          a0.s[j] = (unsigned short)(u[j] & 0xffffu);
          a1.s[j] = (unsigned short)(u[j] >> 16);
        }
        *(f16x8*)(cb + cswz(nidx, oct * 16)) = a0.v;
        *(f16x8*)(cb + cswz(nidx, 256 + oct * 16)) = a1.v;
      }
    }
    __syncthreads();                 // Ct(tile 0) ready

    for (int t = 0; t < ntiles; ++t) {
      const int nb = n_start + t * 32;
      int nn = nodes_blk - t * 32; if (nn > 32) nn = 32;
      const int ncf = (nn + 15) >> 4;
      int nnn = nodes_blk - (t + 1) * 32; if (nnn > 32) nnn = 32;

      // ---- prefetch tile t+1 (latency hides under MFMA + step-2)
      if (t + 1 < ntiles) {
        if (lv == 0) {
          const int nodeL = r8 >> 1, child = r8 & 1;
          const int lp = 2 * (nb + 32 + nodeL) + child;
          const int tt = lp >> 6, pp = lp & 63;
          const int g = tt * NPT + 2 * pp - __popc(pp);
          const int wi = word_idx[g];
          const float* src = embed + (size_t)wi * HID + seg * 16;
          ef0 = ((const float4*)src)[0]; ef1 = ((const float4*)src)[1];
          ef2 = ((const float4*)src)[2]; ef3 = ((const float4*)src)[3];
        } else {
          if (nidx < nnn) {
#pragma unroll
            for (int j = 0; j < 8; ++j)
              u[j] = cload(Hp + (size_t)(oct * 8 + j) * NW + 2 * (nb + 32 + nidx));
          }
        }
      }

      f32x4 acc[2][2];
#pragma unroll
      for (int rf = 0; rf < 2; ++rf)
#pragma unroll
        for (int cf = 0; cf < 2; ++cf) { f32x4 z = {0.f, 0.f, 0.f, 0.f}; acc[rf][cf] = z; }

#pragma unroll
      for (int lc = 0; lc < 8; ++lc) {
        f16x8 Af[2];
#pragma unroll
        for (int rf = 0; rf < 2; ++rf)
          Af[rf] = *(const f16x8*)(ab + cswz(w * 32 + rf * 16 + lo16, lc * 64 + q * 16));
#pragma unroll
        for (int cf = 0; cf < 2; ++cf) {
          if (cf < ncf) {
            const int nl = cf * 16 + lo16;
            const f16x8 Bf = *(const f16x8*)(cb + cswz(nl, lc * 64 + q * 16));
#pragma unroll
            for (int rf = 0; rf < 2; ++rf)
              acc[rf][cf] = __builtin_amdgcn_mfma_f32_16x16x32_f16(Af[rf], Bf, acc[rf][cf], 0, 0, 0);
          }
        }
      }

      // ---- step-2: part[n] = sum_k c_n[k]*(T[k,n] + W[k,h]); c fp16 from LDS
      float pt[2];
#pragma unroll
      for (int cf = 0; cf < 2; ++cf) {
        pt[cf] = 0.f;
        if (cf < ncf) {
          const int nl = cf * 16 + lo16;
          float s = 0.f;
#pragma unroll
          for (int rf = 0; rf < 2; ++rf) {
            const int kb = w * 32 + rf * 16 + q * 4;
            const f16x4 cv = *(const f16x4*)(cb + cswz(nl, kb * 2));
            s += (float)cv[0] * (acc[rf][cf][0] + wk[rf][0])
               + (float)cv[1] * (acc[rf][cf][1] + wk[rf][1])
               + (float)cv[2] * (acc[rf][cf][2] + wk[rf][2])
               + (float)cv[3] * (acc[rf][cf][3] + wk[rf][3]);
          }
          pt[cf] = s;
        }
      }
#pragma unroll
      for (int cf = 0; cf < 2; ++cf) {
        pt[cf] += __shfl_xor(pt[cf], 16);
        pt[cf] += __shfl_xor(pt[cf], 32);
      }
      if (q == 0) {
#pragma unroll
        for (int cf = 0; cf < 2; ++cf)
          if (cf < ncf) red[w][cf * 16 + lo16] = pt[cf];
      }
      __syncthreads();               // red ready; all Ct reads done

      // ---- store (reads red only) || stage tile t+1 into Ct (from regs)
      if (tid < (nn >> 1)) {
        float x0 = bh, x1 = bh;
#pragma unroll
        for (int ww = 0; ww < 8; ++ww) {
          x0 += red[ww][2 * tid];
          x1 += red[ww][2 * tid + 1];
        }
        const float t0 = tanhf(x0), t1 = tanhf(x1);
        union { _Float16 f; unsigned short s; } c0, c1;
        c0.f = (_Float16)t0; c1.f = (_Float16)t1;
        const int n0 = nb + 2 * tid;
        cstore(Hn + (size_t)h * NW + n0, (unsigned)c0.s | ((unsigned)c1.s << 16));
        const int mask = (1 << lognpt) - 1;
        const int g0 = ((n0) >> lognpt) * NPT + tree_idx(n0 & mask, sst);
        const int g1 = ((n0 + 1) >> lognpt) * NPT + tree_idx((n0 + 1) & mask, sst);
        cstoref(Hgt + (size_t)h * 2048 + g0, t0);
        cstoref(Hgt + (size_t)h * 2048 + g1, t1);
      }
      if (t + 1 < ntiles) {
        if (lv == 0) {
          const int nodeL = r8 >> 1, child = r8 & 1;
          f16x8 v0, v1;
          v0[0] = (_Float16)ef0.x; v0[1] = (_Float16)ef0.y;
          v0[2] = (_Float16)ef0.z; v0[3] = (_Float16)ef0.w;
          v0[4] = (_Float16)ef1.x; v0[5] = (_Float16)ef1.y;
          v0[6] = (_Float16)ef1.z; v0[7] = (_Float16)ef1.w;
          v1[0] = (_Float16)ef2.x; v1[1] = (_Float16)ef2.y;
          v1[2] = (_Float16)ef2.z; v1[3] = (_Float16)ef2.w;
          v1[4] = (_Float16)ef3.x; v1[5] = (_Float16)ef3.y;
          v1[6] = (_Float16)ef3.z; v1[7] = (_Float16)ef3.w;
          *(f16x8*)(cb + cswz(nodeL, child * 256 + seg * 32)) = v0;
          *(f16x8*)(cb + cswz(nodeL, child * 256 + seg * 32 + 16)) = v1;
          if (seg == hseg) {
            const int lp = 2 * (nb + 32 + nodeL) + child;
            const int tt = lp >> 6, pp = lp & 63;
            const int g = tt * NPT + 2 * pp - __popc(pp);
            cstoref(Hgt + (size_t)h * 2048 + g, pick16(ef0, ef1, ef2, ef3, hcomp));
          }
        } else {
          if (nidx < nnn) {
            union { f16x8 v; unsigned short s[8]; } a0, a1;
#pragma unroll
            for (int j = 0; j < 8; ++j) {
              a0.s[j] = (unsigned short)(u[j] & 0xffffu);
              a1.s[j] = (unsigned short)(u[j] >> 16);
            }
            *(f16x8*)(cb + cswz(nidx, oct * 16)) = a0.v;
            *(f16x8*)(cb + cswz(nidx, 256 + oct * 16)) = a1.v;
          }
        }
      }
      __syncthreads();               // Ct(t+1) ready; red free
    }
    gbar(syncb, lv);
  }

  // ---- output epilogue: block b (<127) owns nodes b*16 .. b*16+15
  if (bid < 127 && tid < 256) {
    const int node = bid * 16 + (tid >> 4);
    const int hs = tid & 15;
    float l0 = 0.f, l1 = 0.f, l2 = 0.f, l3 = 0.f, l4 = 0.f;
#pragma unroll
    for (int j = 0; j < 8; ++j) {
      const int hh = hs + j * 16;
      const float x = cloadf(Hgt + (size_t)hh * 2048 + node);
      const float* wr = Wout + (size_t)hh * 5;
      l0 += x * wr[0]; l1 += x * wr[1]; l2 += x * wr[2];
      l3 += x * wr[3]; l4 += x * wr[4];
    }
#pragma unroll
    for (int d = 1; d < 16; d <<= 1) {
      l0 += __shfl_xor(l0, d); l1 += __shfl_xor(l1, d); l2 += __shfl_xor(l2, d);
      l3 += __shfl_xor(l3, d); l4 += __shfl_xor(l4, d);
    }
    if (hs == 0) {
      l0 += Wb[0]; l1 += Wb[1]; l2 += Wb[2]; l3 += Wb[3]; l4 += Wb[4];
      const float mm = fmaxf(fmaxf(fmaxf(l0, l1), fmaxf(l2, l3)), l4);
      const float ss = expf(l0 - mm) + expf(l1 - mm) + expf(l2 - mm)
                     + expf(l3 - mm) + expf(l4 - mm);
      const float lse = mm + logf(ss);
      float* o = out + (size_t)node * 5;
      o[0] = l0 - lse; o[1] = l1 - lse; o[2] = l2 - lse; o[3] = l3 - lse; o[4] = l4 - lse;
    }
  }
}

extern "C" void kernel_launch(void* const* d_in, const int* in_sizes, int n_in,
                              void* d_out, int out_size, void* d_ws, size_t ws_size,
                              hipStream_t stream) {
  const float* embed = (const float*)d_in[0];
  const float* V     = (const float*)d_in[1];
  const float* W     = (const float*)d_in[2];
  const float* b     = (const float*)d_in[3];
  const float* Wout  = (const float*)d_in[4];
  const float* Woutb = (const float*)d_in[5];
  // d_in[6/8/9] = is_leaf/left/right: tree structure is implicit
  const int* word_idx = (const int*)d_in[7];
  float* out = (float*)d_out;

  // ws: H16A | H16B | Hgt | sync
  char* wsb = (char*)d_ws;
  _Float16* H16A = (_Float16*)wsb;                      // 128*1024*2 = 262144
  _Float16* H16B = (_Float16*)(wsb + 262144);           //              262144
  float*    Hgt  = (float*)(wsb + 524288);              // 128*2048*4 = 1048576
  int*     syncb = (int*)(wsb + 1572864);               //               24576

  hipMemsetAsync(syncb, 0, 24576, stream);
  rntn_kernel<<<256, 512, 0, stream>>>(V, W, b, embed, word_idx, Wout, Woutb,
                                       H16A, H16B, Hgt, out, syncb);
}

// Round 23
// 70.973 us; speedup vs baseline: 1.1248x; 1.0035x over previous
//
#include <hip/hip_runtime.h>

#define HID 128
#define NODES 2032
#define NPT 127
#define NW 1024

typedef _Float16 f16x8 __attribute__((ext_vector_type(8)));
typedef _Float16 f16x4 __attribute__((ext_vector_type(4)));
typedef float f32x4 __attribute__((ext_vector_type(4)));

// post-order index (within one 127-node tree) of the p-th node at a level
// whose subtree size is sst = 2^(L+1)-1
__device__ __forceinline__ int tree_idx(int p, int sst) {
  return (p + 1) * sst + p - __popc(p) - 1;
}
// swizzled byte address in a [R][256] fp16 tile with 512B rows
__device__ __forceinline__ int cswz(int row, int colbyte) {
  return row * 512 + (colbyte ^ ((row & 31) << 4));
}
// select element i (0..15) from 4 float4 regs (pure cndmask tree, no scratch)
__device__ __forceinline__ float pick16(float4 a, float4 b, float4 c, float4 d, int i) {
  float4 s0x = (i & 8) ? c : a;
  float4 s1x = (i & 8) ? d : b;
  float4 s = (i & 4) ? s1x : s0x;
  float lo = (i & 1) ? s.y : s.x;
  float hi = (i & 1) ? s.w : s.z;
  return (i & 2) ? hi : lo;
}

// Device-coherent 4B access: relaxed agent-scope atomics -> sc1 accesses at
// the device coherence point. No fences, no L2 writeback/invalidate.
__device__ __forceinline__ unsigned int cload(const void* p) {
  return __hip_atomic_load((const unsigned int*)p, __ATOMIC_RELAXED, __HIP_MEMORY_SCOPE_AGENT);
}
__device__ __forceinline__ void cstore(void* p, unsigned int v) {
  __hip_atomic_store((unsigned int*)p, v, __ATOMIC_RELAXED, __HIP_MEMORY_SCOPE_AGENT);
}
__device__ __forceinline__ float cloadf(const void* p) {
  union { unsigned int u; float f; } c; c.u = cload(p); return c.f;
}
__device__ __forceinline__ void cstoref(void* p, float f) {
  union { float f; unsigned int u; } c; c.f = f; cstore(p, c.u);
}

// Pure-relaxed tree barrier for 256 blocks: 16 groups x 16 -> root ->
// 16 per-group release flags (<=16 pollers per flag line). Every wave drains
// its sc1 stores (s_waitcnt vmcnt(0)) BEFORE arriving.
__device__ __forceinline__ void gbar(int* sb, int ph) {
  asm volatile("s_waitcnt vmcnt(0)" ::: "memory");
  __syncthreads();
  if (threadIdx.x == 0) {
    int* base = sb + ph * 1024;
    const int grp = blockIdx.x & 15;
    int v = __hip_atomic_fetch_add(base + grp * 32, 1, __ATOMIC_RELAXED, __HIP_MEMORY_SCOPE_AGENT);
    if (v == 15) {
      int r = __hip_atomic_fetch_add(base + 768, 1, __ATOMIC_RELAXED, __HIP_MEMORY_SCOPE_AGENT);
      if (r == 15) {
#pragma unroll
        for (int gg = 0; gg < 16; ++gg)
          __hip_atomic_store(base + 512 + gg * 16, 1, __ATOMIC_RELAXED, __HIP_MEMORY_SCOPE_AGENT);
      }
    }
    while (!__hip_atomic_load(base + 512 + grp * 16, __ATOMIC_RELAXED, __HIP_MEMORY_SCOPE_AGENT))
      __builtin_amdgcn_s_sleep(4);
  }
  __syncthreads();
}

// Persistent kernel, 256 blocks = (h, part), 512 threads = 8 waves, 1 block/CU.
// A = V[h] fp16 in 128 KB swizzled LDS, staged WAVE-PRIVATE. 6 levels,
// 32-node C-tiles, 2 syncs/tile; node stores DEFERRED one tile (red
// double-buffer) so sc1 store latency hides under the next tile's compute
// instead of being drained by the barrier-implicit vmcnt(0). lv0 stages from
// embed; leaf-Hgt for tile t stored at the TOP of iteration t (ef holds
// tile t's values there — including t=0). 6 relaxed grid barriers;
// log-softmax epilogue in-kernel.
__global__ __launch_bounds__(512, 1) void rntn_kernel(
    const float* __restrict__ V, const float* __restrict__ W, const float* __restrict__ bb,
    const float* __restrict__ embed, const int* __restrict__ word_idx,
    const float* __restrict__ Wout, const float* __restrict__ Wb,
    _Float16* __restrict__ H16A, _Float16* __restrict__ H16B,
    float* __restrict__ Hgt, float* __restrict__ out, int* __restrict__ syncb)
{
  __shared__ _Float16 Alds[256 * 256];  // 128 KB swizzled A (row = k, 512B)
  __shared__ _Float16 Ct[32 * 256];     // 16 KB swizzled C-tile
  __shared__ float red[2][8][32];       // double-buffered partial sums

  const int bid = blockIdx.x;
  const int h = bid >> 1, part = bid & 1;
  const int tid = threadIdx.x, lane = tid & 63, w = tid >> 6;   // w in [0,8)
  const int lo16 = lane & 15, q = lane >> 4;
  const int nidx = tid & 31, oct = tid >> 5;   // lv>0 stage: 32 nodes x 16 octs
  const int r8 = tid >> 3, seg = tid & 7;      // lv0 stage: 64 rows x 8 segs
  const int hseg = h >> 4, hcomp = h & 15;     // which seg/elem holds col h
  char* ab = (char*)Alds;
  char* cb = (char*)Ct;

  // ---- lv0 tile-0 embed gather FIRST (overlaps the A read below)
  float4 ef0, ef1, ef2, ef3;
  {
    const int nodeL = r8 >> 1, child = r8 & 1;
    const int lp = 2 * (part * 256 + nodeL) + child;
    const int tt = lp >> 6, pp = lp & 63;
    const int g = tt * NPT + 2 * pp - __popc(pp);
    const int wi = word_idx[g];
    const float* src = embed + (size_t)wi * HID + seg * 16;
    ef0 = ((const float4*)src)[0]; ef1 = ((const float4*)src)[1];
    ef2 = ((const float4*)src)[2]; ef3 = ((const float4*)src)[3];
  }

  // ---- stage A, WAVE-PRIVATE: thread covers half of row (tid>>1); wave w
  // writes exactly rows [32w,32w+32) and only wave w's MFMA reads them.
  {
    const int arow = tid >> 1, ahalf = tid & 1;
    const float* src = V + (size_t)h * 65536 + (size_t)arow * 256 + ahalf * 128;
#pragma unroll
    for (int u2 = 0; u2 < 16; ++u2) {
      const float4 a = ((const float4*)src)[u2 * 2];
      const float4 b2 = ((const float4*)src)[u2 * 2 + 1];
      f16x8 v;
      v[0] = (_Float16)a.x;  v[1] = (_Float16)a.y;
      v[2] = (_Float16)a.z;  v[3] = (_Float16)a.w;
      v[4] = (_Float16)b2.x; v[5] = (_Float16)b2.y;
      v[6] = (_Float16)b2.z; v[7] = (_Float16)b2.w;
      *(f16x8*)(ab + cswz(arow, ahalf * 256 + u2 * 16)) = v;
    }
  }
  // ---- W strip -> registers (wave w covers k in [32w, 32w+32))
  f32x4 wk[2];
#pragma unroll
  for (int rf = 0; rf < 2; ++rf) {
    const int kb = w * 32 + rf * 16 + q * 4;
#pragma unroll
    for (int i = 0; i < 4; ++i)
      wk[rf][i] = W[(size_t)(kb + i) * HID + h];
  }
  const float bh = bb[h];

  for (int lv = 0; lv < 6; ++lv) {
    const int m = 512 >> lv;
    const int lognpt = 5 - lv;
    const int sst = (1 << (lv + 2)) - 1;
    _Float16* Hp = (lv & 1) ? H16A : H16B;   // prev-level buffer (lv0 unused)
    _Float16* Hn = (lv & 1) ? H16B : H16A;
    const int nodes_blk = m >> 1;
    const int n_start = part * nodes_blk;
    const int ntiles = (nodes_blk + 31) >> 5;

    unsigned int u[8];
    // ---- entry: prefetch + stage tile 0
    if (lv == 0) {
      const int nodeL = r8 >> 1, child = r8 & 1;
      f16x8 v0, v1;
      v0[0] = (_Float16)ef0.x; v0[1] = (_Float16)ef0.y;
      v0[2] = (_Float16)ef0.z; v0[3] = (_Float16)ef0.w;
      v0[4] = (_Float16)ef1.x; v0[5] = (_Float16)ef1.y;
      v0[6] = (_Float16)ef1.z; v0[7] = (_Float16)ef1.w;
      v1[0] = (_Float16)ef2.x; v1[1] = (_Float16)ef2.y;
      v1[2] = (_Float16)ef2.z; v1[3] = (_Float16)ef2.w;
      v1[4] = (_Float16)ef3.x; v1[5] = (_Float16)ef3.y;
      v1[6] = (_Float16)ef3.z; v1[7] = (_Float16)ef3.w;
      *(f16x8*)(cb + cswz(nodeL, child * 256 + seg * 32)) = v0;
      *(f16x8*)(cb + cswz(nodeL, child * 256 + seg * 32 + 16)) = v1;
    } else {
      const int nn0 = nodes_blk > 32 ? 32 : nodes_blk;
      if (nidx < nn0) {
#pragma unroll
        for (int j = 0; j < 8; ++j)
          u[j] = cload(Hp + (size_t)(oct * 8 + j) * NW + 2 * (n_start + nidx));
        union { f16x8 v; unsigned short s[8]; } a0, a1;
#pragma unroll
        for (int j = 0; j < 8; ++j) {
          a0.s[j] = (unsigned short)(u[j] & 0xffffu);
          a1.s[j] = (unsigned short)(u[j] >> 16);
        }
        *(f16x8*)(cb + cswz(nidx, oct * 16)) = a0.v;
        *(f16x8*)(cb + cswz(nidx, 256 + oct * 16)) = a1.v;
      }
    }
    __syncthreads();                 // Ct(tile 0) ready

    int rb = 0, prev_nb = -1, prev_nn = 0;
    for (int t = 0; t < ntiles; ++t) {
      const int nb = n_start + t * 32;
      int nn = nodes_blk - t * 32; if (nn > 32) nn = 32;
      const int ncf = (nn + 15) >> 4;
      int nnn = nodes_blk - (t + 1) * 32; if (nnn > 32) nnn = 32;

      // ---- lv0 leaf-Hgt store for THIS tile (ef holds tile t's values —
      // initial gather at t=0, prefetch otherwise; precedes ef overwrite)
      if (lv == 0 && seg == hseg) {
        const int nodeL = r8 >> 1, child = r8 & 1;
        const int lp = 2 * (nb + nodeL) + child;
        const int tt = lp >> 6, pp = lp & 63;
        const int g = tt * NPT + 2 * pp - __popc(pp);
        cstoref(Hgt + (size_t)h * 2048 + g, pick16(ef0, ef1, ef2, ef3, hcomp));
      }

      // ---- prefetch tile t+1 (latency hides under MFMA + step-2)
      if (t + 1 < ntiles) {
        if (lv == 0) {
          const int nodeL = r8 >> 1, child = r8 & 1;
          const int lp = 2 * (nb + 32 + nodeL) + child;
          const int tt = lp >> 6, pp = lp & 63;
          const int g = tt * NPT + 2 * pp - __popc(pp);
          const int wi = word_idx[g];
          const float* src = embed + (size_t)wi * HID + seg * 16;
          ef0 = ((const float4*)src)[0]; ef1 = ((const float4*)src)[1];
          ef2 = ((const float4*)src)[2]; ef3 = ((const float4*)src)[3];
        } else {
          if (nidx < nnn) {
#pragma unroll
            for (int j = 0; j < 8; ++j)
              u[j] = cload(Hp + (size_t)(oct * 8 + j) * NW + 2 * (nb + 32 + nidx));
          }
        }
      }

      // ---- deferred node store for PREVIOUS tile (reads red[rb^1]; its
      // sc1 stores land during this tile's MFMA + step-2)
      if (prev_nb >= 0 && tid < (prev_nn >> 1)) {
        float x0 = bh, x1 = bh;
#pragma unroll
        for (int ww = 0; ww < 8; ++ww) {
          x0 += red[rb ^ 1][ww][2 * tid];
          x1 += red[rb ^ 1][ww][2 * tid + 1];
        }
        const float t0 = tanhf(x0), t1 = tanhf(x1);
        union { _Float16 f; unsigned short s; } c0, c1;
        c0.f = (_Float16)t0; c1.f = (_Float16)t1;
        const int n0 = prev_nb + 2 * tid;
        cstore(Hn + (size_t)h * NW + n0, (unsigned)c0.s | ((unsigned)c1.s << 16));
        const int mask = (1 << lognpt) - 1;
        const int g0 = ((n0) >> lognpt) * NPT + tree_idx(n0 & mask, sst);
        const int g1 = ((n0 + 1) >> lognpt) * NPT + tree_idx((n0 + 1) & mask, sst);
        cstoref(Hgt + (size_t)h * 2048 + g0, t0);
        cstoref(Hgt + (size_t)h * 2048 + g1, t1);
      }

      f32x4 acc[2][2];
#pragma unroll
      for (int rf = 0; rf < 2; ++rf)
#pragma unroll
        for (int cf = 0; cf < 2; ++cf) { f32x4 z = {0.f, 0.f, 0.f, 0.f}; acc[rf][cf] = z; }

#pragma unroll
      for (int lc = 0; lc < 8; ++lc) {
        f16x8 Af[2];
#pragma unroll
        for (int rf = 0; rf < 2; ++rf)
          Af[rf] = *(const f16x8*)(ab + cswz(w * 32 + rf * 16 + lo16, lc * 64 + q * 16));
#pragma unroll
        for (int cf = 0; cf < 2; ++cf) {
          if (cf < ncf) {
            const int nl = cf * 16 + lo16;
            const f16x8 Bf = *(const f16x8*)(cb + cswz(nl, lc * 64 + q * 16));
#pragma unroll
            for (int rf = 0; rf < 2; ++rf)
              acc[rf][cf] = __builtin_amdgcn_mfma_f32_16x16x32_f16(Af[rf], Bf, acc[rf][cf], 0, 0, 0);
          }
        }
      }

      // ---- step-2: part[n] = sum_k c_n[k]*(T[k,n] + W[k,h]); c fp16 from LDS
      float pt[2];
#pragma unroll
      for (int cf = 0; cf < 2; ++cf) {
        pt[cf] = 0.f;
        if (cf < ncf) {
          const int nl = cf * 16 + lo16;
          float s = 0.f;
#pragma unroll
          for (int rf = 0; rf < 2; ++rf) {
            const int kb = w * 32 + rf * 16 + q * 4;
            const f16x4 cv = *(const f16x4*)(cb + cswz(nl, kb * 2));
            s += (float)cv[0] * (acc[rf][cf][0] + wk[rf][0])
               + (float)cv[1] * (acc[rf][cf][1] + wk[rf][1])
               + (float)cv[2] * (acc[rf][cf][2] + wk[rf][2])
               + (float)cv[3] * (acc[rf][cf][3] + wk[rf][3]);
          }
          pt[cf] = s;
        }
      }
#pragma unroll
      for (int cf = 0; cf < 2; ++cf) {
        pt[cf] += __shfl_xor(pt[cf], 16);
        pt[cf] += __shfl_xor(pt[cf], 32);
      }
      if (q == 0) {
#pragma unroll
        for (int cf = 0; cf < 2; ++cf)
          if (cf < ncf) red[rb][w][cf * 16 + lo16] = pt[cf];
      }
      __syncthreads();               // red[rb] ready; all Ct reads done

      // ---- stage tile t+1 into Ct (from regs)
      if (t + 1 < ntiles) {
        if (lv == 0) {
          const int nodeL = r8 >> 1, child = r8 & 1;
          f16x8 v0, v1;
          v0[0] = (_Float16)ef0.x; v0[1] = (_Float16)ef0.y;
          v0[2] = (_Float16)ef0.z; v0[3] = (_Float16)ef0.w;
          v0[4] = (_Float16)ef1.x; v0[5] = (_Float16)ef1.y;
          v0[6] = (_Float16)ef1.z; v0[7] = (_Float16)ef1.w;
          v1[0] = (_Float16)ef2.x; v1[1] = (_Float16)ef2.y;
          v1[2] = (_Float16)ef2.z; v1[3] = (_Float16)ef2.w;
          v1[4] = (_Float16)ef3.x; v1[5] = (_Float16)ef3.y;
          v1[6] = (_Float16)ef3.z; v1[7] = (_Float16)ef3.w;
          *(f16x8*)(cb + cswz(nodeL, child * 256 + seg * 32)) = v0;
          *(f16x8*)(cb + cswz(nodeL, child * 256 + seg * 32 + 16)) = v1;
        } else {
          if (nidx < nnn) {
            union { f16x8 v; unsigned short s[8]; } a0, a1;
#pragma unroll
            for (int j = 0; j < 8; ++j) {
              a0.s[j] = (unsigned short)(u[j] & 0xffffu);
              a1.s[j] = (unsigned short)(u[j] >> 16);
            }
            *(f16x8*)(cb + cswz(nidx, oct * 16)) = a0.v;
            *(f16x8*)(cb + cswz(nidx, 256 + oct * 16)) = a1.v;
          }
        }
      }
      __syncthreads();               // Ct(t+1) ready; red[rb^1] free
      prev_nb = nb; prev_nn = nn; rb ^= 1;
    }

    // ---- final tile's deferred node store (drained by gbar's vmcnt(0))
    if (prev_nb >= 0 && tid < (prev_nn >> 1)) {
      float x0 = bh, x1 = bh;
#pragma unroll
      for (int ww = 0; ww < 8; ++ww) {
        x0 += red[rb ^ 1][ww][2 * tid];
        x1 += red[rb ^ 1][ww][2 * tid + 1];
      }
      const float t0 = tanhf(x0), t1 = tanhf(x1);
      union { _Float16 f; unsigned short s; } c0, c1;
      c0.f = (_Float16)t0; c1.f = (_Float16)t1;
      const int n0 = prev_nb + 2 * tid;
      cstore(Hn + (size_t)h * NW + n0, (unsigned)c0.s | ((unsigned)c1.s << 16));
      const int mask = (1 << lognpt) - 1;
      const int g0 = ((n0) >> lognpt) * NPT + tree_idx(n0 & mask, sst);
      const int g1 = ((n0 + 1) >> lognpt) * NPT + tree_idx((n0 + 1) & mask, sst);
      cstoref(Hgt + (size_t)h * 2048 + g0, t0);
      cstoref(Hgt + (size_t)h * 2048 + g1, t1);
    }
    gbar(syncb, lv);
  }

  // ---- output epilogue: block b (<127) owns nodes b*16 .. b*16+15
  if (bid < 127 && tid < 256) {
    const int node = bid * 16 + (tid >> 4);
    const int hs = tid & 15;
    float l0 = 0.f, l1 = 0.f, l2 = 0.f, l3 = 0.f, l4 = 0.f;
#pragma unroll
    for (int j = 0; j < 8; ++j) {
      const int hh = hs + j * 16;
      const float x = cloadf(Hgt + (size_t)hh * 2048 + node);
      const float* wr = Wout + (size_t)hh * 5;
      l0 += x * wr[0]; l1 += x * wr[1]; l2 += x * wr[2];
      l3 += x * wr[3]; l4 += x * wr[4];
    }
#pragma unroll
    for (int d = 1; d < 16; d <<= 1) {
      l0 += __shfl_xor(l0, d); l1 += __shfl_xor(l1, d); l2 += __shfl_xor(l2, d);
      l3 += __shfl_xor(l3, d); l4 += __shfl_xor(l4, d);
    }
    if (hs == 0) {
      l0 += Wb[0]; l1 += Wb[1]; l2 += Wb[2]; l3 += Wb[3]; l4 += Wb[4];
      const float mm = fmaxf(fmaxf(fmaxf(l0, l1), fmaxf(l2, l3)), l4);
      const float ss = expf(l0 - mm) + expf(l1 - mm) + expf(l2 - mm)
                     + expf(l3 - mm) + expf(l4 - mm);
      const float lse = mm + logf(ss);
      float* o = out + (size_t)node * 5;
      o[0] = l0 - lse; o[1] = l1 - lse; o[2] = l2 - lse; o[3] = l3 - lse; o[4] = l4 - lse;
    }
  }
}

extern "C" void kernel_launch(void* const* d_in, const int* in_sizes, int n_in,
                              void* d_out, int out_size, void* d_ws, size_t ws_size,
                              hipStream_t stream) {
  const float* embed = (const float*)d_in[0];
  const float* V     = (const float*)d_in[1];
  const float* W     = (const float*)d_in[2];
  const float* b     = (const float*)d_in[3];
  const float* Wout  = (const float*)d_in[4];
  const float* Woutb = (const float*)d_in[5];
  // d_in[6/8/9] = is_leaf/left/right: tree structure is implicit
  const int* word_idx = (const int*)d_in[7];
  float* out = (float*)d_out;

  // ws: H16A | H16B | Hgt | sync
  char* wsb = (char*)d_ws;
  _Float16* H16A = (_Float16*)wsb;                      // 128*1024*2 = 262144
  _Float16* H16B = (_Float16*)(wsb + 262144);           //              262144
  float*    Hgt  = (float*)(wsb + 524288);              // 128*2048*4 = 1048576
  int*     syncb = (int*)(wsb + 1572864);               //               24576

  hipMemsetAsync(syncb, 0, 24576, stream);
  rntn_kernel<<<256, 512, 0, stream>>>(V, W, b, embed, word_idx, Wout, Woutb,
                                       H16A, H16B, Hgt, out, syncb);
}